// Round 11
// baseline (318.535 us; speedup 1.0000x reference)
//
#include <hip/hip_runtime.h>
#include <hip/hip_bf16.h>

// SPRGraphNet: embed -> 2x SAGEConv(mean) -> mean-pool per graph -> linear(64->10)
// Inputs detected fp32 (round 2). bf16 h (round 8). Sort-based CSR (round 10).
// Round 11: (a) agg stored bf16 with non-temporal stores (halves agg traffic,
// keeps h resident in L2 during gather — round 10 showed 60MB of h re-fetch);
// (b) rec packed to 32 bits ((tgt>>9)<<17 | src). Harness ws-poison fills
// (2x43us) are a fixed floor outside our control.

struct WParams {
    const void* p[10];
    int off[11];
};

__device__ __forceinline__ float b2f(unsigned short u) {
    return __uint_as_float(((unsigned)u) << 16);
}
__device__ __forceinline__ unsigned short f2b(float f) {
    unsigned x = __float_as_uint(f);
    return (unsigned short)((x + 0x7fff + ((x >> 16) & 1)) >> 16);   // RNE
}
__device__ __forceinline__ float4 b4_to_f4(ushort4 u) {
    return make_float4(b2f(u.x), b2f(u.y), b2f(u.z), b2f(u.w));
}

// Inline dtype detection: fp32 data read as bf16 shows |v|>100 / NaN.
__device__ __forceinline__ int detect_f32(const void* probe, int n_bf16) {
    __shared__ int bad;
    if (threadIdx.x == 0) bad = 0;
    __syncthreads();
    const __hip_bfloat16* p = (const __hip_bfloat16*)probe;
    int lbad = 0;
    for (int i = threadIdx.x; i < n_bf16; i += blockDim.x) {
        float v = __bfloat162float(p[i]);
        if (!(fabsf(v) <= 100.0f)) lbad = 1;
    }
    if (lbad) atomicOr(&bad, 1);
    __syncthreads();
    return bad;
}

__device__ __forceinline__ float loadf(const void* p, int i, int f32) {
    return f32 ? ((const float*)p)[i]
               : __bfloat162float(((const __hip_bfloat16*)p)[i]);
}

static __global__ void convert_kernel(WParams wp, const void* probe,
                                      float* __restrict__ dst, int total) {
    int f32 = detect_f32(probe, 1024);
    int gid = blockIdx.x * blockDim.x + threadIdx.x;
    if (gid >= total) return;
    int s = 0;
    while (gid >= wp.off[s + 1]) ++s;
    dst[gid] = loadf(wp.p[s], gid - wp.off[s], f32);
}

// Blocks [0,NBE): LDS histogram of tgt&511 over a 4096-edge tile -> H[bin][blk].
// Blocks [NBE,..): embed (ushort4 per thread).
static __global__ __launch_bounds__(256) void hist1_embed_kernel(
        const int* __restrict__ tgt, int* __restrict__ H, int NBE,
        const int* __restrict__ x,
        const float* __restrict__ semb, const float* __restrict__ cemb,
        unsigned short* __restrict__ h, int n_nodes, int n_edges) {
    if (blockIdx.x < (unsigned)NBE) {
        __shared__ int lh[512];
        int t = threadIdx.x;
        lh[t] = 0; lh[t + 256] = 0;
        __syncthreads();
        int base = blockIdx.x * 4096;
        for (int i = t; i < 4096; i += 256) {
            int e = base + i;
            if (e < n_edges) atomicAdd(&lh[tgt[e] & 511], 1);
        }
        __syncthreads();
        H[(size_t)t * NBE + blockIdx.x] = lh[t];
        H[(size_t)(t + 256) * NBE + blockIdx.x] = lh[t + 256];
    } else {
        int gid = (blockIdx.x - NBE) * 256 + threadIdx.x;
        int node = gid >> 4, c4 = (gid & 15) * 4;
        if (node >= n_nodes) return;
        const float* tab;
        int row, c = c4;
        if (c4 < 32) { tab = semb; row = x[node * 2]; }
        else         { tab = cemb; row = x[node * 2 + 1]; c = c4 - 32; }
        const float* p = tab + (size_t)row * 32 + c;
        ushort4 o;
        o.x = f2b(p[0]); o.y = f2b(p[1]); o.z = f2b(p[2]); o.w = f2b(p[3]);
        *(ushort4*)&h[(size_t)node * 64 + c4] = o;
    }
}

// scanA: 512 elements per block (2/thread), block-inclusive -> tmp, sums -> bsum.
static __global__ __launch_bounds__(256) void scanA_kernel(
        const int* __restrict__ in, int* __restrict__ tmp,
        int* __restrict__ bsum, int n) {
    __shared__ int s[256];
    int t = threadIdx.x;
    int i0 = blockIdx.x * 512 + 2 * t;
    int a0 = (i0 < n) ? in[i0] : 0;
    int a1 = (i0 + 1 < n) ? in[i0 + 1] : 0;
    s[t] = a0 + a1;
    __syncthreads();
#pragma unroll
    for (int d = 1; d < 256; d <<= 1) {
        int x = (t >= d) ? s[t - d] : 0;
        __syncthreads();
        s[t] += x;
        __syncthreads();
    }
    if (i0 < n) tmp[i0] = s[t] - a1;          // inclusive at i0
    if (i0 + 1 < n) tmp[i0 + 1] = s[t];       // inclusive at i0+1
    if (t == 255) bsum[blockIdx.x] = s[255];
}

static __global__ __launch_bounds__(1024) void scan2_kernel(
        int* __restrict__ bsum, int nb) {     // in-place inclusive scan, nb <= 1024
    __shared__ int s[1024];
    int t = threadIdx.x;
    s[t] = (t < nb) ? bsum[t] : 0;
    __syncthreads();
#pragma unroll
    for (int d = 1; d < 1024; d <<= 1) {
        int x = (t >= d) ? s[t - d] : 0;
        __syncthreads();
        s[t] += x;
        __syncthreads();
    }
    if (t < nb) bsum[t] = s[t];
}

// scanC: B[i] = global exclusive prefix of H at i.
static __global__ __launch_bounds__(256) void scanC_kernel(
        const int* __restrict__ tmp, const int* __restrict__ bsum,
        const int* __restrict__ H, int* __restrict__ B, int n) {
    int i = blockIdx.x * 256 + threadIdx.x;
    if (i >= n) return;
    int blk = i / 512;
    int basep = (blk > 0) ? bsum[blk - 1] : 0;
    B[i] = tmp[i] + basep - H[i];
}

// scatter1: re-read tile; LDS cursors seeded from B give global slots directly.
// Write packed 32-bit records ((tgt>>9)<<17 | src) grouped by bucket.
static __global__ __launch_bounds__(256) void scatter1_kernel(
        const int* __restrict__ src, const int* __restrict__ tgt,
        const int* __restrict__ B, unsigned* __restrict__ rec,
        int NBE, int n_edges) {
    __shared__ int cur[512];
    int t = threadIdx.x;
    cur[t]       = B[(size_t)t * NBE + blockIdx.x];
    cur[t + 256] = B[(size_t)(t + 256) * NBE + blockIdx.x];
    __syncthreads();
    int base = blockIdx.x * 4096;
    for (int i = t; i < 4096; i += 256) {
        int e = base + i;
        if (e < n_edges) {
            int tg = tgt[e];
            int pos = atomicAdd(&cur[tg & 511], 1);
            rec[pos] = ((unsigned)(tg >> 9) << 17) | (unsigned)src[e];
        }
    }
}

// csr2: one block per bucket b. Records [B[b*NBE], next) share tgt&511==b;
// q = rec>>17 (<196), node = b + (q<<9). LDS hist+scan -> start/cnt + scatter.
static __global__ __launch_bounds__(256) void csr2_kernel(
        const unsigned* __restrict__ rec, const int* __restrict__ B,
        int NBE, int* __restrict__ csr_src,
        int* __restrict__ startA, int* __restrict__ cntA,
        int n_nodes, int n_edges) {
    __shared__ int hist[256], scn[256], cursor[256];
    __shared__ int sbeg, send;
    int b = blockIdx.x;
    int t = threadIdx.x;
    hist[t] = 0;
    if (t == 0) {
        sbeg = B[(size_t)b * NBE];
        send = (b == 511) ? n_edges : B[(size_t)(b + 1) * NBE];
    }
    __syncthreads();
    int beg = sbeg, end = send;
    for (int i = beg + t; i < end; i += 256) {
        atomicAdd(&hist[rec[i] >> 17], 1);
    }
    __syncthreads();
    scn[t] = hist[t];
    __syncthreads();
#pragma unroll
    for (int d = 1; d < 256; d <<= 1) {
        int x = (t >= d) ? scn[t - d] : 0;
        __syncthreads();
        scn[t] += x;
        __syncthreads();
    }
    int excl = scn[t] - hist[t];
    cursor[t] = beg + excl;
    int n = b + (t << 9);
    if (n < n_nodes) { startA[n] = beg + excl; cntA[n] = hist[t]; }
    __syncthreads();
    for (int i = beg + t; i < end; i += 256) {
        unsigned r = rec[i];
        int p = atomicAdd(&cursor[r >> 17], 1);
        csr_src[p] = (int)(r & 0x1FFFFu);
    }
}

// One wave per node. lane = 16*g + j: group g handles edges (i % 4 == g),
// lane loads ushort4 (4 bf16 cols). Cross-group reduce via shfl_xor.
// agg written bf16 via non-temporal store (keep h resident in L2).
static __global__ __launch_bounds__(256) void gather_kernel(
        const unsigned short* __restrict__ h, const int* __restrict__ startA,
        const int* __restrict__ cntA,
        const int* __restrict__ csr_src, unsigned short* __restrict__ aggb,
        int n_nodes) {
    int node = (blockIdx.x * 256 + threadIdx.x) >> 6;
    int lane = threadIdx.x & 63;
    if (node >= n_nodes) return;
    int g = lane >> 4, j = lane & 15;
    int beg = startA[node], deg = cntA[node];
    int end = beg + deg;

    float4 acc = make_float4(0.f, 0.f, 0.f, 0.f);
    int i = beg + g;
    for (; i + 12 < end; i += 16) {
        int s0 = csr_src[i];
        int s1 = csr_src[i + 4];
        int s2 = csr_src[i + 8];
        int s3 = csr_src[i + 12];
        float4 v0 = b4_to_f4(*reinterpret_cast<const ushort4*>(h + (size_t)s0 * 64 + j * 4));
        float4 v1 = b4_to_f4(*reinterpret_cast<const ushort4*>(h + (size_t)s1 * 64 + j * 4));
        float4 v2 = b4_to_f4(*reinterpret_cast<const ushort4*>(h + (size_t)s2 * 64 + j * 4));
        float4 v3 = b4_to_f4(*reinterpret_cast<const ushort4*>(h + (size_t)s3 * 64 + j * 4));
        acc.x += v0.x + v1.x + v2.x + v3.x;
        acc.y += v0.y + v1.y + v2.y + v3.y;
        acc.z += v0.z + v1.z + v2.z + v3.z;
        acc.w += v0.w + v1.w + v2.w + v3.w;
    }
    for (; i + 4 < end; i += 8) {
        int s0 = csr_src[i];
        int s1 = csr_src[i + 4];
        float4 v0 = b4_to_f4(*reinterpret_cast<const ushort4*>(h + (size_t)s0 * 64 + j * 4));
        float4 v1 = b4_to_f4(*reinterpret_cast<const ushort4*>(h + (size_t)s1 * 64 + j * 4));
        acc.x += v0.x + v1.x;
        acc.y += v0.y + v1.y;
        acc.z += v0.z + v1.z;
        acc.w += v0.w + v1.w;
    }
    if (i < end) {
        int s = csr_src[i];
        float4 v = b4_to_f4(*reinterpret_cast<const ushort4*>(h + (size_t)s * 64 + j * 4));
        acc.x += v.x; acc.y += v.y; acc.z += v.z; acc.w += v.w;
    }
#pragma unroll
    for (int m = 16; m < 64; m <<= 1) {
        acc.x += __shfl_xor(acc.x, m, 64);
        acc.y += __shfl_xor(acc.y, m, 64);
        acc.z += __shfl_xor(acc.z, m, 64);
        acc.w += __shfl_xor(acc.w, m, 64);
    }
    if (g == 0) {
        float inv = 1.0f / fmaxf((float)deg, 1.0f);
        ushort4 o;
        o.x = f2b(acc.x * inv); o.y = f2b(acc.y * inv);
        o.z = f2b(acc.z * inv); o.w = f2b(acc.w * inv);
        unsigned long long bits;
        __builtin_memcpy(&bits, &o, 8);
        __builtin_nontemporal_store(
            bits, (unsigned long long*)(aggb + (size_t)node * 64 + j * 4));
    }
}

// h = relu([agg | h] @ [wl; wr] + b), in place (bf16 h + bf16 agg, fp32 math).
static __global__ __launch_bounds__(256) void layer_kernel(
        unsigned short* __restrict__ h, const unsigned short* __restrict__ aggb,
        const float* __restrict__ wl, const float* __restrict__ wr,
        const float* __restrict__ b, int n_nodes) {
    __shared__ float inS[64][132];   // [node][k], +4 pad
    __shared__ float wS[128][64];    // [k][col], rows 0..63 = wl, 64..127 = wr
    int t = threadIdx.x;
    int base = blockIdx.x * 64;

    const float4* wl4 = (const float4*)wl;
    const float4* wr4 = (const float4*)wr;
#pragma unroll
    for (int r = 0; r < 4; ++r) {
        int i = t + 256 * r;
        int k = i >> 4, c = (i & 15) * 4;
        *(float4*)&wS[k][c] = wl4[i];
        *(float4*)&wS[64 + k][c] = wr4[i];
    }
#pragma unroll
    for (int r = 0; r < 4; ++r) {
        int i = t + 256 * r;
        int n = i >> 4, c = (i & 15) * 4;
        int node = base + n;
        float4 va = make_float4(0.f, 0.f, 0.f, 0.f);
        float4 vh = make_float4(0.f, 0.f, 0.f, 0.f);
        if (node < n_nodes) {
            va = b4_to_f4(*(const ushort4*)&aggb[(size_t)node * 64 + c]);
            vh = b4_to_f4(*(const ushort4*)&h[(size_t)node * 64 + c]);
        }
        *(float4*)&inS[n][c] = va;
        *(float4*)&inS[n][64 + c] = vh;
    }
    __syncthreads();

    int tx = t & 15, ty = t >> 4;
    int c0 = tx * 4, n0 = ty * 4;
    float4 bias = *(const float4*)&b[c0];
    float acc[4][4];
#pragma unroll
    for (int i = 0; i < 4; ++i) {
        acc[i][0] = bias.x; acc[i][1] = bias.y;
        acc[i][2] = bias.z; acc[i][3] = bias.w;
    }

#pragma unroll 4
    for (int k = 0; k < 128; k += 4) {
        float4 a0 = *(const float4*)&inS[n0 + 0][k];
        float4 a1 = *(const float4*)&inS[n0 + 1][k];
        float4 a2 = *(const float4*)&inS[n0 + 2][k];
        float4 a3 = *(const float4*)&inS[n0 + 3][k];
        float4 w0 = *(const float4*)&wS[k + 0][c0];
        float4 w1 = *(const float4*)&wS[k + 1][c0];
        float4 w2 = *(const float4*)&wS[k + 2][c0];
        float4 w3 = *(const float4*)&wS[k + 3][c0];
#define ROW(i, ai)                                                        \
        acc[i][0] = fmaf(ai.x, w0.x, fmaf(ai.y, w1.x, fmaf(ai.z, w2.x,    \
                    fmaf(ai.w, w3.x, acc[i][0]))));                       \
        acc[i][1] = fmaf(ai.x, w0.y, fmaf(ai.y, w1.y, fmaf(ai.z, w2.y,    \
                    fmaf(ai.w, w3.y, acc[i][1]))));                       \
        acc[i][2] = fmaf(ai.x, w0.z, fmaf(ai.y, w1.z, fmaf(ai.z, w2.z,    \
                    fmaf(ai.w, w3.z, acc[i][2]))));                       \
        acc[i][3] = fmaf(ai.x, w0.w, fmaf(ai.y, w1.w, fmaf(ai.z, w2.w,    \
                    fmaf(ai.w, w3.w, acc[i][3]))));
        ROW(0, a0) ROW(1, a1) ROW(2, a2) ROW(3, a3)
#undef ROW
    }

#pragma unroll
    for (int i = 0; i < 4; ++i) {
        int node = base + n0 + i;
        if (node < n_nodes) {
            ushort4 o;
            o.x = f2b(fmaxf(acc[i][0], 0.f));
            o.y = f2b(fmaxf(acc[i][1], 0.f));
            o.z = f2b(fmaxf(acc[i][2], 0.f));
            o.w = f2b(fmaxf(acc[i][3], 0.f));
            *(ushort4*)&h[(size_t)node * 64 + c0] = o;
        }
    }
}

// batch is sorted: binary-search [start,end) per graph; mean-pool then classify.
static __global__ __launch_bounds__(256) void pool_classify_kernel(
        const unsigned short* __restrict__ h, const int* __restrict__ batch,
        const float* __restrict__ wc, const float* __restrict__ bc,
        void* __restrict__ out, const void* probe, int n_nodes) {
    int f32 = detect_f32(probe, 1024);
    int g = blockIdx.x;
    int t = threadIdx.x;
    int lo = 0, hi = n_nodes;
    while (lo < hi) { int mid = (lo + hi) >> 1; if (batch[mid] < g) lo = mid + 1; else hi = mid; }
    int start = lo;
    hi = n_nodes;
    while (lo < hi) { int mid = (lo + hi) >> 1; if (batch[mid] < g + 1) lo = mid + 1; else hi = mid; }
    int end = lo;

    int r = t >> 6, o = t & 63;
    float partial = 0.0f;
    for (int n = start + r; n < end; n += 4) partial += b2f(h[(size_t)n * 64 + o]);
    __shared__ float sred[4][64];
    __shared__ float pooled[64];
    sred[r][o] = partial;
    __syncthreads();
    if (r == 0) {
        float cntf = fmaxf((float)(end - start), 1.0f);
        pooled[o] = (sred[0][o] + sred[1][o] + sred[2][o] + sred[3][o]) / cntf;
    }
    __syncthreads();
    if (t < 10) {
        float acc = bc[t];
#pragma unroll
        for (int k = 0; k < 64; ++k)
            acc = fmaf(pooled[k], wc[k * 10 + t], acc);
        if (f32) ((float*)out)[g * 10 + t] = acc;
        else     ((__hip_bfloat16*)out)[g * 10 + t] = __float2bfloat16(acc);
    }
}

extern "C" void kernel_launch(void* const* d_in, const int* in_sizes, int n_in,
                              void* d_out, int out_size, void* d_ws, size_t ws_size,
                              hipStream_t stream) {
    const int* x          = (const int*)d_in[0];
    const int* edge_index = (const int*)d_in[1];
    const int* batch      = (const int*)d_in[2];

    const int N = in_sizes[2];        // N_NODES
    const int E = in_sizes[1] / 2;    // edge_index is (2, E)
    const int G = out_size / 10;      // num_graphs

    const int NBE = (E + 4095) / 4096;          // edge tiles
    const int Hsz = 512 * NBE;                  // histogram matrix size
    const int SB  = (Hsz + 511) / 512;          // scanA blocks (<=1024)
    const int MB  = (N * 16 + 255) / 256;       // embed blocks

    // workspace layout
    unsigned short* h    = (unsigned short*)d_ws;           // N*64 bf16
    unsigned short* aggb = h + (size_t)N * 64;              // N*64 bf16
    unsigned* rec   = (unsigned*)(aggb + (size_t)N * 64);   // E packed
    int*   startA  = (int*)(rec + E);                       // N
    int*   cntA    = startA + N;                            // N
    int*   H       = cntA + N;                              // Hsz
    int*   B       = H + Hsz;                               // Hsz
    int*   tmpS    = B + Hsz;                               // Hsz
    int*   bsumS   = tmpS + Hsz;                            // SB (<=1024)
    int*   csr_src = bsumS + 1024;                          // E
    float* wbuf    = (float*)(csr_src + E);

    WParams wp;
    int off = 0;
    for (int i = 0; i < 10; ++i) {
        wp.p[i] = d_in[4 + i];
        wp.off[i] = off;
        off += in_sizes[4 + i];
    }
    wp.off[10] = off;
    const int wtotal = off;

    float* semb_f = wbuf + wp.off[0];
    float* cemb_f = wbuf + wp.off[1];
    float* w1l_f  = wbuf + wp.off[2];
    float* w1r_f  = wbuf + wp.off[3];
    float* b1_f   = wbuf + wp.off[4];
    float* w2l_f  = wbuf + wp.off[5];
    float* w2r_f  = wbuf + wp.off[6];
    float* b2_f   = wbuf + wp.off[7];
    float* wc_f   = wbuf + wp.off[8];
    float* bc_f   = wbuf + wp.off[9];

    const int* src = edge_index;
    const int* tgt = edge_index + E;

    convert_kernel<<<(wtotal + 255) / 256, 256, 0, stream>>>(wp, d_in[4], wbuf, wtotal);

    // CSR build by counting sort (no global returning atomics, no memset)
    hist1_embed_kernel<<<NBE + MB, 256, 0, stream>>>(tgt, H, NBE, x, semb_f,
                                                     cemb_f, h, N, E);
    scanA_kernel<<<SB, 256, 0, stream>>>(H, tmpS, bsumS, Hsz);
    scan2_kernel<<<1, 1024, 0, stream>>>(bsumS, SB);
    scanC_kernel<<<(Hsz + 255) / 256, 256, 0, stream>>>(tmpS, bsumS, H, B, Hsz);
    scatter1_kernel<<<NBE, 256, 0, stream>>>(src, tgt, B, rec, NBE, E);
    csr2_kernel<<<512, 256, 0, stream>>>(rec, B, NBE, csr_src, startA, cntA, N, E);

    // layer 1
    gather_kernel<<<(N * 64 + 255) / 256, 256, 0, stream>>>(h, startA, cntA, csr_src, aggb, N);
    layer_kernel<<<(N + 63) / 64, 256, 0, stream>>>(h, aggb, w1l_f, w1r_f, b1_f, N);

    // layer 2
    gather_kernel<<<(N * 64 + 255) / 256, 256, 0, stream>>>(h, startA, cntA, csr_src, aggb, N);
    layer_kernel<<<(N + 63) / 64, 256, 0, stream>>>(h, aggb, w2l_f, w2r_f, b2_f, N);

    // pool + classify
    pool_classify_kernel<<<G, 256, 0, stream>>>(h, batch, wc_f, bc_f, d_out, d_in[4], N);
}

// Round 12
// 307.571 us; speedup vs baseline: 1.0356x; 1.0356x over previous
//
#include <hip/hip_runtime.h>
#include <hip/hip_bf16.h>

// SPRGraphNet: embed -> 2x SAGEConv(mean) -> mean-pool per graph -> linear(64->10)
// Inputs detected fp32 (round 2). bf16 h (round 8). Sort-based CSR (round 10).
// Round 12: gather restructured to 8 lanes/edge with 16B (b128) loads —
// 1KB/wave-instruction coalescing, half the vmem instructions and address
// math of the 16-lane/edge version (round 11: VALUBusy 49%, instruction-issue
// co-limited). nt store dropped (round 11: pushed agg to HBM, no gather gain).

struct WParams {
    const void* p[10];
    int off[11];
};

__device__ __forceinline__ float b2f(unsigned short u) {
    return __uint_as_float(((unsigned)u) << 16);
}
__device__ __forceinline__ unsigned short f2b(float f) {
    unsigned x = __float_as_uint(f);
    return (unsigned short)((x + 0x7fff + ((x >> 16) & 1)) >> 16);   // RNE
}
__device__ __forceinline__ float4 b4_to_f4(ushort4 u) {
    return make_float4(b2f(u.x), b2f(u.y), b2f(u.z), b2f(u.w));
}
__device__ __forceinline__ float blo(unsigned u) {   // low bf16 of a dword
    return __uint_as_float(u << 16);
}
__device__ __forceinline__ float bhi(unsigned u) {   // high bf16 of a dword
    return __uint_as_float(u & 0xffff0000u);
}

// Inline dtype detection: fp32 data read as bf16 shows |v|>100 / NaN.
__device__ __forceinline__ int detect_f32(const void* probe, int n_bf16) {
    __shared__ int bad;
    if (threadIdx.x == 0) bad = 0;
    __syncthreads();
    const __hip_bfloat16* p = (const __hip_bfloat16*)probe;
    int lbad = 0;
    for (int i = threadIdx.x; i < n_bf16; i += blockDim.x) {
        float v = __bfloat162float(p[i]);
        if (!(fabsf(v) <= 100.0f)) lbad = 1;
    }
    if (lbad) atomicOr(&bad, 1);
    __syncthreads();
    return bad;
}

__device__ __forceinline__ float loadf(const void* p, int i, int f32) {
    return f32 ? ((const float*)p)[i]
               : __bfloat162float(((const __hip_bfloat16*)p)[i]);
}

static __global__ void convert_kernel(WParams wp, const void* probe,
                                      float* __restrict__ dst, int total) {
    int f32 = detect_f32(probe, 1024);
    int gid = blockIdx.x * blockDim.x + threadIdx.x;
    if (gid >= total) return;
    int s = 0;
    while (gid >= wp.off[s + 1]) ++s;
    dst[gid] = loadf(wp.p[s], gid - wp.off[s], f32);
}

// Blocks [0,NBE): LDS histogram of tgt&511 over a 4096-edge tile -> H[bin][blk].
// Blocks [NBE,..): embed (ushort4 per thread).
static __global__ __launch_bounds__(256) void hist1_embed_kernel(
        const int* __restrict__ tgt, int* __restrict__ H, int NBE,
        const int* __restrict__ x,
        const float* __restrict__ semb, const float* __restrict__ cemb,
        unsigned short* __restrict__ h, int n_nodes, int n_edges) {
    if (blockIdx.x < (unsigned)NBE) {
        __shared__ int lh[512];
        int t = threadIdx.x;
        lh[t] = 0; lh[t + 256] = 0;
        __syncthreads();
        int base = blockIdx.x * 4096;
        for (int i = t; i < 4096; i += 256) {
            int e = base + i;
            if (e < n_edges) atomicAdd(&lh[tgt[e] & 511], 1);
        }
        __syncthreads();
        H[(size_t)t * NBE + blockIdx.x] = lh[t];
        H[(size_t)(t + 256) * NBE + blockIdx.x] = lh[t + 256];
    } else {
        int gid = (blockIdx.x - NBE) * 256 + threadIdx.x;
        int node = gid >> 4, c4 = (gid & 15) * 4;
        if (node >= n_nodes) return;
        const float* tab;
        int row, c = c4;
        if (c4 < 32) { tab = semb; row = x[node * 2]; }
        else         { tab = cemb; row = x[node * 2 + 1]; c = c4 - 32; }
        const float* p = tab + (size_t)row * 32 + c;
        ushort4 o;
        o.x = f2b(p[0]); o.y = f2b(p[1]); o.z = f2b(p[2]); o.w = f2b(p[3]);
        *(ushort4*)&h[(size_t)node * 64 + c4] = o;
    }
}

// scanA: 512 elements per block (2/thread), block-inclusive -> tmp, sums -> bsum.
static __global__ __launch_bounds__(256) void scanA_kernel(
        const int* __restrict__ in, int* __restrict__ tmp,
        int* __restrict__ bsum, int n) {
    __shared__ int s[256];
    int t = threadIdx.x;
    int i0 = blockIdx.x * 512 + 2 * t;
    int a0 = (i0 < n) ? in[i0] : 0;
    int a1 = (i0 + 1 < n) ? in[i0 + 1] : 0;
    s[t] = a0 + a1;
    __syncthreads();
#pragma unroll
    for (int d = 1; d < 256; d <<= 1) {
        int x = (t >= d) ? s[t - d] : 0;
        __syncthreads();
        s[t] += x;
        __syncthreads();
    }
    if (i0 < n) tmp[i0] = s[t] - a1;          // inclusive at i0
    if (i0 + 1 < n) tmp[i0 + 1] = s[t];       // inclusive at i0+1
    if (t == 255) bsum[blockIdx.x] = s[255];
}

static __global__ __launch_bounds__(1024) void scan2_kernel(
        int* __restrict__ bsum, int nb) {     // in-place inclusive scan, nb <= 1024
    __shared__ int s[1024];
    int t = threadIdx.x;
    s[t] = (t < nb) ? bsum[t] : 0;
    __syncthreads();
#pragma unroll
    for (int d = 1; d < 1024; d <<= 1) {
        int x = (t >= d) ? s[t - d] : 0;
        __syncthreads();
        s[t] += x;
        __syncthreads();
    }
    if (t < nb) bsum[t] = s[t];
}

// scanC: B[i] = global exclusive prefix of H at i.
static __global__ __launch_bounds__(256) void scanC_kernel(
        const int* __restrict__ tmp, const int* __restrict__ bsum,
        const int* __restrict__ H, int* __restrict__ B, int n) {
    int i = blockIdx.x * 256 + threadIdx.x;
    if (i >= n) return;
    int blk = i / 512;
    int basep = (blk > 0) ? bsum[blk - 1] : 0;
    B[i] = tmp[i] + basep - H[i];
}

// scatter1: re-read tile; LDS cursors seeded from B give global slots directly.
// Write packed 32-bit records ((tgt>>9)<<17 | src) grouped by bucket.
static __global__ __launch_bounds__(256) void scatter1_kernel(
        const int* __restrict__ src, const int* __restrict__ tgt,
        const int* __restrict__ B, unsigned* __restrict__ rec,
        int NBE, int n_edges) {
    __shared__ int cur[512];
    int t = threadIdx.x;
    cur[t]       = B[(size_t)t * NBE + blockIdx.x];
    cur[t + 256] = B[(size_t)(t + 256) * NBE + blockIdx.x];
    __syncthreads();
    int base = blockIdx.x * 4096;
    for (int i = t; i < 4096; i += 256) {
        int e = base + i;
        if (e < n_edges) {
            int tg = tgt[e];
            int pos = atomicAdd(&cur[tg & 511], 1);
            rec[pos] = ((unsigned)(tg >> 9) << 17) | (unsigned)src[e];
        }
    }
}

// csr2: one block per bucket b. Records [B[b*NBE], next) share tgt&511==b;
// q = rec>>17 (<196), node = b + (q<<9). LDS hist+scan -> start/cnt + scatter.
static __global__ __launch_bounds__(256) void csr2_kernel(
        const unsigned* __restrict__ rec, const int* __restrict__ B,
        int NBE, int* __restrict__ csr_src,
        int* __restrict__ startA, int* __restrict__ cntA,
        int n_nodes, int n_edges) {
    __shared__ int hist[256], scn[256], cursor[256];
    __shared__ int sbeg, send;
    int b = blockIdx.x;
    int t = threadIdx.x;
    hist[t] = 0;
    if (t == 0) {
        sbeg = B[(size_t)b * NBE];
        send = (b == 511) ? n_edges : B[(size_t)(b + 1) * NBE];
    }
    __syncthreads();
    int beg = sbeg, end = send;
    for (int i = beg + t; i < end; i += 256) {
        atomicAdd(&hist[rec[i] >> 17], 1);
    }
    __syncthreads();
    scn[t] = hist[t];
    __syncthreads();
#pragma unroll
    for (int d = 1; d < 256; d <<= 1) {
        int x = (t >= d) ? scn[t - d] : 0;
        __syncthreads();
        scn[t] += x;
        __syncthreads();
    }
    int excl = scn[t] - hist[t];
    cursor[t] = beg + excl;
    int n = b + (t << 9);
    if (n < n_nodes) { startA[n] = beg + excl; cntA[n] = hist[t]; }
    __syncthreads();
    for (int i = beg + t; i < end; i += 256) {
        unsigned r = rec[i];
        int p = atomicAdd(&cursor[r >> 17], 1);
        csr_src[p] = (int)(r & 0x1FFFFu);
    }
}

// One wave per node. 8 groups x 8 lanes: group g takes edges i == g (mod 8),
// lane j loads ushort8 (16B, cols [8j,8j+8)) -> 1KB per wave instruction.
// 2-deep unroll (16 loads in flight). Cross-group reduce via shfl_xor 8/16/32.
static __global__ __launch_bounds__(256) void gather_kernel(
        const unsigned short* __restrict__ h, const int* __restrict__ startA,
        const int* __restrict__ cntA,
        const int* __restrict__ csr_src, unsigned short* __restrict__ aggb,
        int n_nodes) {
    int node = (blockIdx.x * 256 + threadIdx.x) >> 6;
    int lane = threadIdx.x & 63;
    if (node >= n_nodes) return;
    int g = lane >> 3, j = lane & 7;
    int beg = startA[node], deg = cntA[node];
    int end = beg + deg;

    float acc[8];
#pragma unroll
    for (int k = 0; k < 8; ++k) acc[k] = 0.f;

    int i = beg + g;
    for (; i + 8 < end; i += 16) {
        int s0 = csr_src[i];
        int s1 = csr_src[i + 8];
        uint4 u0 = *reinterpret_cast<const uint4*>(h + (size_t)s0 * 64 + j * 8);
        uint4 u1 = *reinterpret_cast<const uint4*>(h + (size_t)s1 * 64 + j * 8);
        acc[0] += blo(u0.x) + blo(u1.x);
        acc[1] += bhi(u0.x) + bhi(u1.x);
        acc[2] += blo(u0.y) + blo(u1.y);
        acc[3] += bhi(u0.y) + bhi(u1.y);
        acc[4] += blo(u0.z) + blo(u1.z);
        acc[5] += bhi(u0.z) + bhi(u1.z);
        acc[6] += blo(u0.w) + blo(u1.w);
        acc[7] += bhi(u0.w) + bhi(u1.w);
    }
    if (i < end) {
        int s = csr_src[i];
        uint4 u = *reinterpret_cast<const uint4*>(h + (size_t)s * 64 + j * 8);
        acc[0] += blo(u.x); acc[1] += bhi(u.x);
        acc[2] += blo(u.y); acc[3] += bhi(u.y);
        acc[4] += blo(u.z); acc[5] += bhi(u.z);
        acc[6] += blo(u.w); acc[7] += bhi(u.w);
    }
#pragma unroll
    for (int m = 8; m < 64; m <<= 1) {
#pragma unroll
        for (int k = 0; k < 8; ++k) acc[k] += __shfl_xor(acc[k], m, 64);
    }
    if (g == 0) {
        float inv = 1.0f / fmaxf((float)deg, 1.0f);
        uint4 o;
        o.x = ((unsigned)f2b(acc[1] * inv) << 16) | f2b(acc[0] * inv);
        o.y = ((unsigned)f2b(acc[3] * inv) << 16) | f2b(acc[2] * inv);
        o.z = ((unsigned)f2b(acc[5] * inv) << 16) | f2b(acc[4] * inv);
        o.w = ((unsigned)f2b(acc[7] * inv) << 16) | f2b(acc[6] * inv);
        *reinterpret_cast<uint4*>(aggb + (size_t)node * 64 + j * 8) = o;
    }
}

// h = relu([agg | h] @ [wl; wr] + b), in place (bf16 h + bf16 agg, fp32 math).
static __global__ __launch_bounds__(256) void layer_kernel(
        unsigned short* __restrict__ h, const unsigned short* __restrict__ aggb,
        const float* __restrict__ wl, const float* __restrict__ wr,
        const float* __restrict__ b, int n_nodes) {
    __shared__ float inS[64][132];   // [node][k], +4 pad
    __shared__ float wS[128][64];    // [k][col], rows 0..63 = wl, 64..127 = wr
    int t = threadIdx.x;
    int base = blockIdx.x * 64;

    const float4* wl4 = (const float4*)wl;
    const float4* wr4 = (const float4*)wr;
#pragma unroll
    for (int r = 0; r < 4; ++r) {
        int i = t + 256 * r;
        int k = i >> 4, c = (i & 15) * 4;
        *(float4*)&wS[k][c] = wl4[i];
        *(float4*)&wS[64 + k][c] = wr4[i];
    }
#pragma unroll
    for (int r = 0; r < 4; ++r) {
        int i = t + 256 * r;
        int n = i >> 4, c = (i & 15) * 4;
        int node = base + n;
        float4 va = make_float4(0.f, 0.f, 0.f, 0.f);
        float4 vh = make_float4(0.f, 0.f, 0.f, 0.f);
        if (node < n_nodes) {
            va = b4_to_f4(*(const ushort4*)&aggb[(size_t)node * 64 + c]);
            vh = b4_to_f4(*(const ushort4*)&h[(size_t)node * 64 + c]);
        }
        *(float4*)&inS[n][c] = va;
        *(float4*)&inS[n][64 + c] = vh;
    }
    __syncthreads();

    int tx = t & 15, ty = t >> 4;
    int c0 = tx * 4, n0 = ty * 4;
    float4 bias = *(const float4*)&b[c0];
    float acc[4][4];
#pragma unroll
    for (int i = 0; i < 4; ++i) {
        acc[i][0] = bias.x; acc[i][1] = bias.y;
        acc[i][2] = bias.z; acc[i][3] = bias.w;
    }

#pragma unroll 4
    for (int k = 0; k < 128; k += 4) {
        float4 a0 = *(const float4*)&inS[n0 + 0][k];
        float4 a1 = *(const float4*)&inS[n0 + 1][k];
        float4 a2 = *(const float4*)&inS[n0 + 2][k];
        float4 a3 = *(const float4*)&inS[n0 + 3][k];
        float4 w0 = *(const float4*)&wS[k + 0][c0];
        float4 w1 = *(const float4*)&wS[k + 1][c0];
        float4 w2 = *(const float4*)&wS[k + 2][c0];
        float4 w3 = *(const float4*)&wS[k + 3][c0];
#define ROW(i, ai)                                                        \
        acc[i][0] = fmaf(ai.x, w0.x, fmaf(ai.y, w1.x, fmaf(ai.z, w2.x,    \
                    fmaf(ai.w, w3.x, acc[i][0]))));                       \
        acc[i][1] = fmaf(ai.x, w0.y, fmaf(ai.y, w1.y, fmaf(ai.z, w2.y,    \
                    fmaf(ai.w, w3.y, acc[i][1]))));                       \
        acc[i][2] = fmaf(ai.x, w0.z, fmaf(ai.y, w1.z, fmaf(ai.z, w2.z,    \
                    fmaf(ai.w, w3.z, acc[i][2]))));                       \
        acc[i][3] = fmaf(ai.x, w0.w, fmaf(ai.y, w1.w, fmaf(ai.z, w2.w,    \
                    fmaf(ai.w, w3.w, acc[i][3]))));
        ROW(0, a0) ROW(1, a1) ROW(2, a2) ROW(3, a3)
#undef ROW
    }

#pragma unroll
    for (int i = 0; i < 4; ++i) {
        int node = base + n0 + i;
        if (node < n_nodes) {
            ushort4 o;
            o.x = f2b(fmaxf(acc[i][0], 0.f));
            o.y = f2b(fmaxf(acc[i][1], 0.f));
            o.z = f2b(fmaxf(acc[i][2], 0.f));
            o.w = f2b(fmaxf(acc[i][3], 0.f));
            *(ushort4*)&h[(size_t)node * 64 + c0] = o;
        }
    }
}

// batch is sorted: binary-search [start,end) per graph; mean-pool then classify.
static __global__ __launch_bounds__(256) void pool_classify_kernel(
        const unsigned short* __restrict__ h, const int* __restrict__ batch,
        const float* __restrict__ wc, const float* __restrict__ bc,
        void* __restrict__ out, const void* probe, int n_nodes) {
    int f32 = detect_f32(probe, 1024);
    int g = blockIdx.x;
    int t = threadIdx.x;
    int lo = 0, hi = n_nodes;
    while (lo < hi) { int mid = (lo + hi) >> 1; if (batch[mid] < g) lo = mid + 1; else hi = mid; }
    int start = lo;
    hi = n_nodes;
    while (lo < hi) { int mid = (lo + hi) >> 1; if (batch[mid] < g + 1) lo = mid + 1; else hi = mid; }
    int end = lo;

    int r = t >> 6, o = t & 63;
    float partial = 0.0f;
    for (int n = start + r; n < end; n += 4) partial += b2f(h[(size_t)n * 64 + o]);
    __shared__ float sred[4][64];
    __shared__ float pooled[64];
    sred[r][o] = partial;
    __syncthreads();
    if (r == 0) {
        float cntf = fmaxf((float)(end - start), 1.0f);
        pooled[o] = (sred[0][o] + sred[1][o] + sred[2][o] + sred[3][o]) / cntf;
    }
    __syncthreads();
    if (t < 10) {
        float acc = bc[t];
#pragma unroll
        for (int k = 0; k < 64; ++k)
            acc = fmaf(pooled[k], wc[k * 10 + t], acc);
        if (f32) ((float*)out)[g * 10 + t] = acc;
        else     ((__hip_bfloat16*)out)[g * 10 + t] = __float2bfloat16(acc);
    }
}

extern "C" void kernel_launch(void* const* d_in, const int* in_sizes, int n_in,
                              void* d_out, int out_size, void* d_ws, size_t ws_size,
                              hipStream_t stream) {
    const int* x          = (const int*)d_in[0];
    const int* edge_index = (const int*)d_in[1];
    const int* batch      = (const int*)d_in[2];

    const int N = in_sizes[2];        // N_NODES
    const int E = in_sizes[1] / 2;    // edge_index is (2, E)
    const int G = out_size / 10;      // num_graphs

    const int NBE = (E + 4095) / 4096;          // edge tiles
    const int Hsz = 512 * NBE;                  // histogram matrix size
    const int SB  = (Hsz + 511) / 512;          // scanA blocks (<=1024)
    const int MB  = (N * 16 + 255) / 256;       // embed blocks

    // workspace layout
    unsigned short* h    = (unsigned short*)d_ws;           // N*64 bf16
    unsigned short* aggb = h + (size_t)N * 64;              // N*64 bf16
    unsigned* rec   = (unsigned*)(aggb + (size_t)N * 64);   // E packed
    int*   startA  = (int*)(rec + E);                       // N
    int*   cntA    = startA + N;                            // N
    int*   H       = cntA + N;                              // Hsz
    int*   B       = H + Hsz;                               // Hsz
    int*   tmpS    = B + Hsz;                               // Hsz
    int*   bsumS   = tmpS + Hsz;                            // SB (<=1024)
    int*   csr_src = bsumS + 1024;                          // E
    float* wbuf    = (float*)(csr_src + E);

    WParams wp;
    int off = 0;
    for (int i = 0; i < 10; ++i) {
        wp.p[i] = d_in[4 + i];
        wp.off[i] = off;
        off += in_sizes[4 + i];
    }
    wp.off[10] = off;
    const int wtotal = off;

    float* semb_f = wbuf + wp.off[0];
    float* cemb_f = wbuf + wp.off[1];
    float* w1l_f  = wbuf + wp.off[2];
    float* w1r_f  = wbuf + wp.off[3];
    float* b1_f   = wbuf + wp.off[4];
    float* w2l_f  = wbuf + wp.off[5];
    float* w2r_f  = wbuf + wp.off[6];
    float* b2_f   = wbuf + wp.off[7];
    float* wc_f   = wbuf + wp.off[8];
    float* bc_f   = wbuf + wp.off[9];

    const int* src = edge_index;
    const int* tgt = edge_index + E;

    convert_kernel<<<(wtotal + 255) / 256, 256, 0, stream>>>(wp, d_in[4], wbuf, wtotal);

    // CSR build by counting sort (no global returning atomics, no memset)
    hist1_embed_kernel<<<NBE + MB, 256, 0, stream>>>(tgt, H, NBE, x, semb_f,
                                                     cemb_f, h, N, E);
    scanA_kernel<<<SB, 256, 0, stream>>>(H, tmpS, bsumS, Hsz);
    scan2_kernel<<<1, 1024, 0, stream>>>(bsumS, SB);
    scanC_kernel<<<(Hsz + 255) / 256, 256, 0, stream>>>(tmpS, bsumS, H, B, Hsz);
    scatter1_kernel<<<NBE, 256, 0, stream>>>(src, tgt, B, rec, NBE, E);
    csr2_kernel<<<512, 256, 0, stream>>>(rec, B, NBE, csr_src, startA, cntA, N, E);

    // layer 1
    gather_kernel<<<(N * 64 + 255) / 256, 256, 0, stream>>>(h, startA, cntA, csr_src, aggb, N);
    layer_kernel<<<(N + 63) / 64, 256, 0, stream>>>(h, aggb, w1l_f, w1r_f, b1_f, N);

    // layer 2
    gather_kernel<<<(N * 64 + 255) / 256, 256, 0, stream>>>(h, startA, cntA, csr_src, aggb, N);
    layer_kernel<<<(N + 63) / 64, 256, 0, stream>>>(h, aggb, w2l_f, w2r_f, b2_f, N);

    // pool + classify
    pool_classify_kernel<<<G, 256, 0, stream>>>(h, batch, wc_f, bc_f, d_out, d_in[4], N);
}

// Round 15
// 302.139 us; speedup vs baseline: 1.0543x; 1.0180x over previous
//
#include <hip/hip_runtime.h>
#include <hip/hip_bf16.h>

// SPRGraphNet: embed -> 2x SAGEConv(mean) -> mean-pool per graph -> linear(64->10)
// Inputs detected fp32 (round 2). bf16 h (round 8). Sort-based CSR (round 10).
// Round 15: REVERT gather to round-12 version (round 14's shfl-broadcast
// gather had a real accuracy bug: absmax 9.77e-4 -> 5.55e-3; the 2^-10
// baseline was invariant across r8-r12 reorderings, so the jump = bug, not
// noise). Keep vec4 (plain int4, not nt-builtin) tgt/src loads in
// hist1/scatter1 — value-identical, only changes which thread issues which
// LDS atomic. Harness poison fills (~88us/iter at 76% HBM peak) = floor.

struct WParams {
    const void* p[10];
    int off[11];
};

__device__ __forceinline__ float b2f(unsigned short u) {
    return __uint_as_float(((unsigned)u) << 16);
}
__device__ __forceinline__ unsigned short f2b(float f) {
    unsigned x = __float_as_uint(f);
    return (unsigned short)((x + 0x7fff + ((x >> 16) & 1)) >> 16);   // RNE
}
__device__ __forceinline__ float4 b4_to_f4(ushort4 u) {
    return make_float4(b2f(u.x), b2f(u.y), b2f(u.z), b2f(u.w));
}
__device__ __forceinline__ float blo(unsigned u) {   // low bf16 of a dword
    return __uint_as_float(u << 16);
}
__device__ __forceinline__ float bhi(unsigned u) {   // high bf16 of a dword
    return __uint_as_float(u & 0xffff0000u);
}

// Inline dtype detection: fp32 data read as bf16 shows |v|>100 / NaN.
__device__ __forceinline__ int detect_f32(const void* probe, int n_bf16) {
    __shared__ int bad;
    if (threadIdx.x == 0) bad = 0;
    __syncthreads();
    const __hip_bfloat16* p = (const __hip_bfloat16*)probe;
    int lbad = 0;
    for (int i = threadIdx.x; i < n_bf16; i += blockDim.x) {
        float v = __bfloat162float(p[i]);
        if (!(fabsf(v) <= 100.0f)) lbad = 1;
    }
    if (lbad) atomicOr(&bad, 1);
    __syncthreads();
    return bad;
}

__device__ __forceinline__ float loadf(const void* p, int i, int f32) {
    return f32 ? ((const float*)p)[i]
               : __bfloat162float(((const __hip_bfloat16*)p)[i]);
}

static __global__ void convert_kernel(WParams wp, const void* probe,
                                      float* __restrict__ dst, int total) {
    int f32 = detect_f32(probe, 1024);
    int gid = blockIdx.x * blockDim.x + threadIdx.x;
    if (gid >= total) return;
    int s = 0;
    while (gid >= wp.off[s + 1]) ++s;
    dst[gid] = loadf(wp.p[s], gid - wp.off[s], f32);
}

// Blocks [0,NBE): LDS histogram of tgt&511 over a 4096-edge tile -> H[bin][blk].
// Blocks [NBE,..): embed (ushort4 per thread).
static __global__ __launch_bounds__(256) void hist1_embed_kernel(
        const int* __restrict__ tgt, int* __restrict__ H, int NBE,
        const int* __restrict__ x,
        const float* __restrict__ semb, const float* __restrict__ cemb,
        unsigned short* __restrict__ h, int n_nodes, int n_edges) {
    if (blockIdx.x < (unsigned)NBE) {
        __shared__ int lh[512];
        int t = threadIdx.x;
        lh[t] = 0; lh[t + 256] = 0;
        __syncthreads();
        int base = blockIdx.x * 4096;              // multiple of 4
        const int4* tgt4 = (const int4*)tgt + (base >> 2);
#pragma unroll
        for (int r = 0; r < 4; ++r) {
            int i4 = t + 256 * r;
            int e = base + i4 * 4;
            if (e + 3 < n_edges) {
                int4 v = tgt4[i4];
                atomicAdd(&lh[v.x & 511], 1);
                atomicAdd(&lh[v.y & 511], 1);
                atomicAdd(&lh[v.z & 511], 1);
                atomicAdd(&lh[v.w & 511], 1);
            } else {
                for (int q = 0; q < 4; ++q) {
                    int ee = e + q;
                    if (ee < n_edges) atomicAdd(&lh[tgt[ee] & 511], 1);
                }
            }
        }
        __syncthreads();
        H[(size_t)t * NBE + blockIdx.x] = lh[t];
        H[(size_t)(t + 256) * NBE + blockIdx.x] = lh[t + 256];
    } else {
        int gid = (blockIdx.x - NBE) * 256 + threadIdx.x;
        int node = gid >> 4, c4 = (gid & 15) * 4;
        if (node >= n_nodes) return;
        const float* tab;
        int row, c = c4;
        if (c4 < 32) { tab = semb; row = x[node * 2]; }
        else         { tab = cemb; row = x[node * 2 + 1]; c = c4 - 32; }
        const float* p = tab + (size_t)row * 32 + c;
        ushort4 o;
        o.x = f2b(p[0]); o.y = f2b(p[1]); o.z = f2b(p[2]); o.w = f2b(p[3]);
        *(ushort4*)&h[(size_t)node * 64 + c4] = o;
    }
}

// scanA: 512 elements per block (2/thread), block-inclusive -> tmp, sums -> bsum.
static __global__ __launch_bounds__(256) void scanA_kernel(
        const int* __restrict__ in, int* __restrict__ tmp,
        int* __restrict__ bsum, int n) {
    __shared__ int s[256];
    int t = threadIdx.x;
    int i0 = blockIdx.x * 512 + 2 * t;
    int a0 = (i0 < n) ? in[i0] : 0;
    int a1 = (i0 + 1 < n) ? in[i0 + 1] : 0;
    s[t] = a0 + a1;
    __syncthreads();
#pragma unroll
    for (int d = 1; d < 256; d <<= 1) {
        int x = (t >= d) ? s[t - d] : 0;
        __syncthreads();
        s[t] += x;
        __syncthreads();
    }
    if (i0 < n) tmp[i0] = s[t] - a1;          // inclusive at i0
    if (i0 + 1 < n) tmp[i0 + 1] = s[t];       // inclusive at i0+1
    if (t == 255) bsum[blockIdx.x] = s[255];
}

static __global__ __launch_bounds__(1024) void scan2_kernel(
        int* __restrict__ bsum, int nb) {     // in-place inclusive scan, nb <= 1024
    __shared__ int s[1024];
    int t = threadIdx.x;
    s[t] = (t < nb) ? bsum[t] : 0;
    __syncthreads();
#pragma unroll
    for (int d = 1; d < 1024; d <<= 1) {
        int x = (t >= d) ? s[t - d] : 0;
        __syncthreads();
        s[t] += x;
        __syncthreads();
    }
    if (t < nb) bsum[t] = s[t];
}

// scanC: B[i] = global exclusive prefix of H at i.
static __global__ __launch_bounds__(256) void scanC_kernel(
        const int* __restrict__ tmp, const int* __restrict__ bsum,
        const int* __restrict__ H, int* __restrict__ B, int n) {
    int i = blockIdx.x * 256 + threadIdx.x;
    if (i >= n) return;
    int blk = i / 512;
    int basep = (blk > 0) ? bsum[blk - 1] : 0;
    B[i] = tmp[i] + basep - H[i];
}

// scatter1: re-read tile; LDS cursors seeded from B give global slots directly.
// Write packed 32-bit records ((tgt>>9)<<17 | src) grouped by bucket.
static __global__ __launch_bounds__(256) void scatter1_kernel(
        const int* __restrict__ src, const int* __restrict__ tgt,
        const int* __restrict__ B, unsigned* __restrict__ rec,
        int NBE, int n_edges) {
    __shared__ int cur[512];
    int t = threadIdx.x;
    cur[t]       = B[(size_t)t * NBE + blockIdx.x];
    cur[t + 256] = B[(size_t)(t + 256) * NBE + blockIdx.x];
    __syncthreads();
    int base = blockIdx.x * 4096;
    const int4* tgt4 = (const int4*)tgt + (base >> 2);
    const int4* src4 = (const int4*)src + (base >> 2);
#pragma unroll
    for (int r = 0; r < 4; ++r) {
        int i4 = t + 256 * r;
        int e = base + i4 * 4;
        if (e + 3 < n_edges) {
            int4 tv = tgt4[i4];
            int4 sv = src4[i4];
            int p0 = atomicAdd(&cur[tv.x & 511], 1);
            rec[p0] = ((unsigned)(tv.x >> 9) << 17) | (unsigned)sv.x;
            int p1 = atomicAdd(&cur[tv.y & 511], 1);
            rec[p1] = ((unsigned)(tv.y >> 9) << 17) | (unsigned)sv.y;
            int p2 = atomicAdd(&cur[tv.z & 511], 1);
            rec[p2] = ((unsigned)(tv.z >> 9) << 17) | (unsigned)sv.z;
            int p3 = atomicAdd(&cur[tv.w & 511], 1);
            rec[p3] = ((unsigned)(tv.w >> 9) << 17) | (unsigned)sv.w;
        } else {
            for (int q = 0; q < 4; ++q) {
                int ee = e + q;
                if (ee < n_edges) {
                    int tg = tgt[ee];
                    int pos = atomicAdd(&cur[tg & 511], 1);
                    rec[pos] = ((unsigned)(tg >> 9) << 17) | (unsigned)src[ee];
                }
            }
        }
    }
}

// csr2: one block per bucket b. Records [B[b*NBE], next) share tgt&511==b;
// q = rec>>17 (<196), node = b + (q<<9). LDS hist+scan -> start/cnt + scatter.
static __global__ __launch_bounds__(256) void csr2_kernel(
        const unsigned* __restrict__ rec, const int* __restrict__ B,
        int NBE, int* __restrict__ csr_src,
        int* __restrict__ startA, int* __restrict__ cntA,
        int n_nodes, int n_edges) {
    __shared__ int hist[256], scn[256], cursor[256];
    __shared__ int sbeg, send;
    int b = blockIdx.x;
    int t = threadIdx.x;
    hist[t] = 0;
    if (t == 0) {
        sbeg = B[(size_t)b * NBE];
        send = (b == 511) ? n_edges : B[(size_t)(b + 1) * NBE];
    }
    __syncthreads();
    int beg = sbeg, end = send;
    for (int i = beg + t; i < end; i += 256) {
        atomicAdd(&hist[rec[i] >> 17], 1);
    }
    __syncthreads();
    scn[t] = hist[t];
    __syncthreads();
#pragma unroll
    for (int d = 1; d < 256; d <<= 1) {
        int x = (t >= d) ? scn[t - d] : 0;
        __syncthreads();
        scn[t] += x;
        __syncthreads();
    }
    int excl = scn[t] - hist[t];
    cursor[t] = beg + excl;
    int n = b + (t << 9);
    if (n < n_nodes) { startA[n] = beg + excl; cntA[n] = hist[t]; }
    __syncthreads();
    for (int i = beg + t; i < end; i += 256) {
        unsigned r = rec[i];
        int p = atomicAdd(&cursor[r >> 17], 1);
        csr_src[p] = (int)(r & 0x1FFFFu);
    }
}

// One wave per node. 8 groups x 8 lanes: group g takes edges i == g (mod 8),
// lane j loads ushort8 (16B, cols [8j,8j+8)) -> 1KB per wave instruction.
// 2-deep unroll (16 loads in flight). Cross-group reduce via shfl_xor 8/16/32.
// (round-12 version — verified absmax 2^-10)
static __global__ __launch_bounds__(256) void gather_kernel(
        const unsigned short* __restrict__ h, const int* __restrict__ startA,
        const int* __restrict__ cntA,
        const int* __restrict__ csr_src, unsigned short* __restrict__ aggb,
        int n_nodes) {
    int node = (blockIdx.x * 256 + threadIdx.x) >> 6;
    int lane = threadIdx.x & 63;
    if (node >= n_nodes) return;
    int g = lane >> 3, j = lane & 7;
    int beg = startA[node], deg = cntA[node];
    int end = beg + deg;

    float acc[8];
#pragma unroll
    for (int k = 0; k < 8; ++k) acc[k] = 0.f;

    int i = beg + g;
    for (; i + 8 < end; i += 16) {
        int s0 = csr_src[i];
        int s1 = csr_src[i + 8];
        uint4 u0 = *reinterpret_cast<const uint4*>(h + (size_t)s0 * 64 + j * 8);
        uint4 u1 = *reinterpret_cast<const uint4*>(h + (size_t)s1 * 64 + j * 8);
        acc[0] += blo(u0.x) + blo(u1.x);
        acc[1] += bhi(u0.x) + bhi(u1.x);
        acc[2] += blo(u0.y) + blo(u1.y);
        acc[3] += bhi(u0.y) + bhi(u1.y);
        acc[4] += blo(u0.z) + blo(u1.z);
        acc[5] += bhi(u0.z) + bhi(u1.z);
        acc[6] += blo(u0.w) + blo(u1.w);
        acc[7] += bhi(u0.w) + bhi(u1.w);
    }
    if (i < end) {
        int s = csr_src[i];
        uint4 u = *reinterpret_cast<const uint4*>(h + (size_t)s * 64 + j * 8);
        acc[0] += blo(u.x); acc[1] += bhi(u.x);
        acc[2] += blo(u.y); acc[3] += bhi(u.y);
        acc[4] += blo(u.z); acc[5] += bhi(u.z);
        acc[6] += blo(u.w); acc[7] += bhi(u.w);
    }
#pragma unroll
    for (int m = 8; m < 64; m <<= 1) {
#pragma unroll
        for (int k = 0; k < 8; ++k) acc[k] += __shfl_xor(acc[k], m, 64);
    }
    if (g == 0) {
        float inv = 1.0f / fmaxf((float)deg, 1.0f);
        uint4 o;
        o.x = ((unsigned)f2b(acc[1] * inv) << 16) | f2b(acc[0] * inv);
        o.y = ((unsigned)f2b(acc[3] * inv) << 16) | f2b(acc[2] * inv);
        o.z = ((unsigned)f2b(acc[5] * inv) << 16) | f2b(acc[4] * inv);
        o.w = ((unsigned)f2b(acc[7] * inv) << 16) | f2b(acc[6] * inv);
        *reinterpret_cast<uint4*>(aggb + (size_t)node * 64 + j * 8) = o;
    }
}

// h = relu([agg | h] @ [wl; wr] + b), in place (bf16 h + bf16 agg, fp32 math).
static __global__ __launch_bounds__(256) void layer_kernel(
        unsigned short* __restrict__ h, const unsigned short* __restrict__ aggb,
        const float* __restrict__ wl, const float* __restrict__ wr,
        const float* __restrict__ b, int n_nodes) {
    __shared__ float inS[64][132];   // [node][k], +4 pad
    __shared__ float wS[128][64];    // [k][col], rows 0..63 = wl, 64..127 = wr
    int t = threadIdx.x;
    int base = blockIdx.x * 64;

    const float4* wl4 = (const float4*)wl;
    const float4* wr4 = (const float4*)wr;
#pragma unroll
    for (int r = 0; r < 4; ++r) {
        int i = t + 256 * r;
        int k = i >> 4, c = (i & 15) * 4;
        *(float4*)&wS[k][c] = wl4[i];
        *(float4*)&wS[64 + k][c] = wr4[i];
    }
#pragma unroll
    for (int r = 0; r < 4; ++r) {
        int i = t + 256 * r;
        int n = i >> 4, c = (i & 15) * 4;
        int node = base + n;
        float4 va = make_float4(0.f, 0.f, 0.f, 0.f);
        float4 vh = make_float4(0.f, 0.f, 0.f, 0.f);
        if (node < n_nodes) {
            va = b4_to_f4(*(const ushort4*)&aggb[(size_t)node * 64 + c]);
            vh = b4_to_f4(*(const ushort4*)&h[(size_t)node * 64 + c]);
        }
        *(float4*)&inS[n][c] = va;
        *(float4*)&inS[n][64 + c] = vh;
    }
    __syncthreads();

    int tx = t & 15, ty = t >> 4;
    int c0 = tx * 4, n0 = ty * 4;
    float4 bias = *(const float4*)&b[c0];
    float acc[4][4];
#pragma unroll
    for (int i = 0; i < 4; ++i) {
        acc[i][0] = bias.x; acc[i][1] = bias.y;
        acc[i][2] = bias.z; acc[i][3] = bias.w;
    }

#pragma unroll 4
    for (int k = 0; k < 128; k += 4) {
        float4 a0 = *(const float4*)&inS[n0 + 0][k];
        float4 a1 = *(const float4*)&inS[n0 + 1][k];
        float4 a2 = *(const float4*)&inS[n0 + 2][k];
        float4 a3 = *(const float4*)&inS[n0 + 3][k];
        float4 w0 = *(const float4*)&wS[k + 0][c0];
        float4 w1 = *(const float4*)&wS[k + 1][c0];
        float4 w2 = *(const float4*)&wS[k + 2][c0];
        float4 w3 = *(const float4*)&wS[k + 3][c0];
#define ROW(i, ai)                                                        \
        acc[i][0] = fmaf(ai.x, w0.x, fmaf(ai.y, w1.x, fmaf(ai.z, w2.x,    \
                    fmaf(ai.w, w3.x, acc[i][0]))));                       \
        acc[i][1] = fmaf(ai.x, w0.y, fmaf(ai.y, w1.y, fmaf(ai.z, w2.y,    \
                    fmaf(ai.w, w3.y, acc[i][1]))));                       \
        acc[i][2] = fmaf(ai.x, w0.z, fmaf(ai.y, w1.z, fmaf(ai.z, w2.z,    \
                    fmaf(ai.w, w3.z, acc[i][2]))));                       \
        acc[i][3] = fmaf(ai.x, w0.w, fmaf(ai.y, w1.w, fmaf(ai.z, w2.w,    \
                    fmaf(ai.w, w3.w, acc[i][3]))));
        ROW(0, a0) ROW(1, a1) ROW(2, a2) ROW(3, a3)
#undef ROW
    }

#pragma unroll
    for (int i = 0; i < 4; ++i) {
        int node = base + n0 + i;
        if (node < n_nodes) {
            ushort4 o;
            o.x = f2b(fmaxf(acc[i][0], 0.f));
            o.y = f2b(fmaxf(acc[i][1], 0.f));
            o.z = f2b(fmaxf(acc[i][2], 0.f));
            o.w = f2b(fmaxf(acc[i][3], 0.f));
            *(ushort4*)&h[(size_t)node * 64 + c0] = o;
        }
    }
}

// batch is sorted: binary-search [start,end) per graph; mean-pool then classify.
static __global__ __launch_bounds__(256) void pool_classify_kernel(
        const unsigned short* __restrict__ h, const int* __restrict__ batch,
        const float* __restrict__ wc, const float* __restrict__ bc,
        void* __restrict__ out, const void* probe, int n_nodes) {
    int f32 = detect_f32(probe, 1024);
    int g = blockIdx.x;
    int t = threadIdx.x;
    int lo = 0, hi = n_nodes;
    while (lo < hi) { int mid = (lo + hi) >> 1; if (batch[mid] < g) lo = mid + 1; else hi = mid; }
    int start = lo;
    hi = n_nodes;
    while (lo < hi) { int mid = (lo + hi) >> 1; if (batch[mid] < g + 1) lo = mid + 1; else hi = mid; }
    int end = lo;

    int r = t >> 6, o = t & 63;
    float partial = 0.0f;
    for (int n = start + r; n < end; n += 4) partial += b2f(h[(size_t)n * 64 + o]);
    __shared__ float sred[4][64];
    __shared__ float pooled[64];
    sred[r][o] = partial;
    __syncthreads();
    if (r == 0) {
        float cntf = fmaxf((float)(end - start), 1.0f);
        pooled[o] = (sred[0][o] + sred[1][o] + sred[2][o] + sred[3][o]) / cntf;
    }
    __syncthreads();
    if (t < 10) {
        float acc = bc[t];
#pragma unroll
        for (int k = 0; k < 64; ++k)
            acc = fmaf(pooled[k], wc[k * 10 + t], acc);
        if (f32) ((float*)out)[g * 10 + t] = acc;
        else     ((__hip_bfloat16*)out)[g * 10 + t] = __float2bfloat16(acc);
    }
}

extern "C" void kernel_launch(void* const* d_in, const int* in_sizes, int n_in,
                              void* d_out, int out_size, void* d_ws, size_t ws_size,
                              hipStream_t stream) {
    const int* x          = (const int*)d_in[0];
    const int* edge_index = (const int*)d_in[1];
    const int* batch      = (const int*)d_in[2];

    const int N = in_sizes[2];        // N_NODES
    const int E = in_sizes[1] / 2;    // edge_index is (2, E)
    const int G = out_size / 10;      // num_graphs

    const int NBE = (E + 4095) / 4096;          // edge tiles
    const int Hsz = 512 * NBE;                  // histogram matrix size
    const int SB  = (Hsz + 511) / 512;          // scanA blocks (<=1024)
    const int MB  = (N * 16 + 255) / 256;       // embed blocks

    // workspace layout
    unsigned short* h    = (unsigned short*)d_ws;           // N*64 bf16
    unsigned short* aggb = h + (size_t)N * 64;              // N*64 bf16
    unsigned* rec   = (unsigned*)(aggb + (size_t)N * 64);   // E packed
    int*   startA  = (int*)(rec + E);                       // N
    int*   cntA    = startA + N;                            // N
    int*   H       = cntA + N;                              // Hsz
    int*   B       = H + Hsz;                               // Hsz
    int*   tmpS    = B + Hsz;                               // Hsz
    int*   bsumS   = tmpS + Hsz;                            // SB (<=1024)
    int*   csr_src = bsumS + 1024;                          // E
    float* wbuf    = (float*)(csr_src + E);

    WParams wp;
    int off = 0;
    for (int i = 0; i < 10; ++i) {
        wp.p[i] = d_in[4 + i];
        wp.off[i] = off;
        off += in_sizes[4 + i];
    }
    wp.off[10] = off;
    const int wtotal = off;

    float* semb_f = wbuf + wp.off[0];
    float* cemb_f = wbuf + wp.off[1];
    float* w1l_f  = wbuf + wp.off[2];
    float* w1r_f  = wbuf + wp.off[3];
    float* b1_f   = wbuf + wp.off[4];
    float* w2l_f  = wbuf + wp.off[5];
    float* w2r_f  = wbuf + wp.off[6];
    float* b2_f   = wbuf + wp.off[7];
    float* wc_f   = wbuf + wp.off[8];
    float* bc_f   = wbuf + wp.off[9];

    const int* src = edge_index;
    const int* tgt = edge_index + E;

    convert_kernel<<<(wtotal + 255) / 256, 256, 0, stream>>>(wp, d_in[4], wbuf, wtotal);

    // CSR build by counting sort (no global returning atomics, no memset)
    hist1_embed_kernel<<<NBE + MB, 256, 0, stream>>>(tgt, H, NBE, x, semb_f,
                                                     cemb_f, h, N, E);
    scanA_kernel<<<SB, 256, 0, stream>>>(H, tmpS, bsumS, Hsz);
    scan2_kernel<<<1, 1024, 0, stream>>>(bsumS, SB);
    scanC_kernel<<<(Hsz + 255) / 256, 256, 0, stream>>>(tmpS, bsumS, H, B, Hsz);
    scatter1_kernel<<<NBE, 256, 0, stream>>>(src, tgt, B, rec, NBE, E);
    csr2_kernel<<<512, 256, 0, stream>>>(rec, B, NBE, csr_src, startA, cntA, N, E);

    // layer 1
    gather_kernel<<<(N * 64 + 255) / 256, 256, 0, stream>>>(h, startA, cntA, csr_src, aggb, N);
    layer_kernel<<<(N + 63) / 64, 256, 0, stream>>>(h, aggb, w1l_f, w1r_f, b1_f, N);

    // layer 2
    gather_kernel<<<(N * 64 + 255) / 256, 256, 0, stream>>>(h, startA, cntA, csr_src, aggb, N);
    layer_kernel<<<(N + 63) / 64, 256, 0, stream>>>(h, aggb, w2l_f, w2r_f, b2_f, N);

    // pool + classify
    pool_classify_kernel<<<G, 256, 0, stream>>>(h, batch, wc_f, bc_f, d_out, d_in[4], N);
}